// Round 4
// baseline (669.256 us; speedup 1.0000x reference)
//
#include <hip/hip_runtime.h>

// ---------------------------------------------------------------------------
// 2-layer GCN + global mean pool, MI355X (gfx950).  ALL-FP32 (inputs are
// float32 per harness contract: "float32 -> const float*"; output float*).
// R1-R3 NaNs were fp32 arrays misread as bf16 (low mantissa halfwords hit
// exp=0xFF patterns ~1/256 -> NaN taps).  Algebra (exact):
//   A_hat = D^{-1/2}(A+I)D^{-1/2}
//   H   = relu( (A_hat X) @ W1 + b1 )        [aggregate-first, GEMM in-place]
//   out = pool( A_hat H ) @ W2 + b2          [pool-first: no relu on layer 2]
// Workspace ~29 MB: CSR (~3.5 MB) + one fp32 [N,128] buffer (25.6 MB) + pool.
// ---------------------------------------------------------------------------

#define D 128
#define NGRAPH 64
#define AGG_BLOCKS 1024   // 4096 waves, one node-chunk per wave

// --- diagnostic: all-zero output (ws too small) ----------------------------
__global__ void zero_out_kernel(float* __restrict__ out, int n) {
    int i = blockIdx.x * blockDim.x + threadIdx.x;
    if (i < n) out[i] = 0.f;
}

// --- CSR build -------------------------------------------------------------
__global__ void count_kernel(const int* __restrict__ ei, int* __restrict__ deg,
                             int E, int N) {
    int e = blockIdx.x * blockDim.x + threadIdx.x;
    if (e < E) {
        int d = ei[E + e];  // dst
        if (d >= 0 && d < N) atomicAdd(&deg[d], 1);
    }
}

__global__ __launch_bounds__(1024) void scan_kernel(const int* __restrict__ deg,
                                                    int* __restrict__ rowstart,
                                                    int* __restrict__ cursor,
                                                    float* __restrict__ dinv, int N) {
    __shared__ int lds[1024];
    int t = threadIdx.x;
    int C = (N + 1023) >> 10;
    int base = t * C;
    int lim = min(base + C, N);
    int s = 0;
    for (int i = base; i < lim; ++i) s += deg[i];
    lds[t] = s;
    __syncthreads();
    int val = s;
    for (int off = 1; off < 1024; off <<= 1) {
        int add = (t >= off) ? lds[t - off] : 0;
        __syncthreads();
        val += add;
        lds[t] = val;
        __syncthreads();
    }
    int running = val - s;  // exclusive prefix
    for (int i = base; i < lim; ++i) {
        rowstart[i] = running;
        cursor[i]   = running;
        running    += deg[i];
        dinv[i]     = rsqrtf((float)deg[i] + 1.0f);  // +1 self loop
    }
    if (t == 1023) rowstart[N] = val;
}

__global__ void fill_kernel(const int* __restrict__ ei, int* __restrict__ cursor,
                            int* __restrict__ colidx, int E, int N) {
    int e = blockIdx.x * blockDim.x + threadIdx.x;
    if (e < E) {
        int d = ei[E + e];
        if (d >= 0 && d < N) {
            int slot = atomicAdd(&cursor[d], 1);
            if (slot >= 0 && slot < E) {
                int s = ei[e];
                colidx[slot] = min(max(s, 0), N - 1);
            }
        }
    }
}

// --- Layer-1 aggregation: AGG_i = dinv_i*(sum_e dinv_s*x_s + dinv_i*x_i) ---
// fp32 in/out. One wave per contiguous node chunk; float2/lane = 512B row.
__global__ __launch_bounds__(256) void agg1_kernel(const float* __restrict__ X,
                                                   const int* __restrict__ rowstart,
                                                   const int* __restrict__ colidx,
                                                   const float* __restrict__ dinv,
                                                   float* __restrict__ AGG,
                                                   int N, int chunk) {
    int gid  = blockIdx.x * 4 + (threadIdx.x >> 6);
    int lane = threadIdx.x & 63;
    int i0 = gid * chunk, i1 = min(i0 + chunk, N);
    for (int i = i0; i < i1; ++i) {
        float di = dinv[i];
        float2 xv = ((const float2*)(X + (size_t)i * D))[lane];
        float ax = di * xv.x, ay = di * xv.y;
        int e0 = rowstart[i], e1 = rowstart[i + 1];
        for (int e = e0; e < e1; ++e) {
            int s = colidx[e];
            float ds = dinv[s];
            float2 sv = ((const float2*)(X + (size_t)s * D))[lane];
            ax = fmaf(ds, sv.x, ax);
            ay = fmaf(ds, sv.y, ay);
        }
        float2 o;
        o.x = di * ax;
        o.y = di * ay;
        ((float2*)(AGG + (size_t)i * D))[lane] = o;
    }
}

// --- In-place GEMM: M = relu(M @ W1 + b1), fp32 vector ALU ------------------
// One wave per 16-row tile (reads of the tile's rows are wave-local broadcast
// loads finished before the tail writes -> in-place safe).
__global__ __launch_bounds__(256) void gemm_relu_kernel(float* __restrict__ M,
                                                        const float* __restrict__ W,
                                                        const float* __restrict__ bias,
                                                        int N) {
    int wave = threadIdx.x >> 6, lane = threadIdx.x & 63;
    int base = (blockIdx.x * 4 + wave) * 16;
    if (base >= N) return;
    int cnt = min(16, N - base);

    size_t rowoff[16];
#pragma unroll
    for (int t = 0; t < 16; ++t) {
        int row = base + t;
        if (row >= N) row = N - 1;          // harmless duplicate reads on tail
        rowoff[t] = (size_t)row * D;
    }

    float2 acc[16];
#pragma unroll
    for (int t = 0; t < 16; ++t) acc[t] = make_float2(0.f, 0.f);

    for (int k = 0; k < D; ++k) {
        float2 w = *(const float2*)(W + k * D + 2 * lane);
#pragma unroll
        for (int t = 0; t < 16; ++t) {
            float a = M[rowoff[t] + k];     // wave-uniform broadcast load
            acc[t].x = fmaf(a, w.x, acc[t].x);
            acc[t].y = fmaf(a, w.y, acc[t].y);
        }
    }
    float2 bv = *(const float2*)(bias + 2 * lane);
    for (int t = 0; t < cnt; ++t) {
        float2 o;
        o.x = fmaxf(acc[t].x + bv.x, 0.f);
        o.y = fmaxf(acc[t].y + bv.y, 0.f);
        ((float2*)(M + (size_t)(base + t) * D))[lane] = o;
    }
}

// --- Layer-2 aggregation fused with pool numerator --------------------------
// batch is sorted: accumulate per-wave locally, flush on graph change.
__global__ __launch_bounds__(256) void agg2_pool_kernel(const float* __restrict__ H,
                                                        const int* __restrict__ rowstart,
                                                        const int* __restrict__ colidx,
                                                        const float* __restrict__ dinv,
                                                        const int* __restrict__ batch,
                                                        float* __restrict__ pool,
                                                        int N, int chunk) {
    int gid  = blockIdx.x * 4 + (threadIdx.x >> 6);
    int lane = threadIdx.x & 63;
    int i0 = gid * chunk, i1 = min(i0 + chunk, N);
    if (i0 >= N) return;

    float2 acc = make_float2(0.f, 0.f);
    int cur = min(max(batch[i0], 0), NGRAPH - 1);
    for (int i = i0; i < i1; ++i) {
        float di = dinv[i];
        float2 hv = ((const float2*)(H + (size_t)i * D))[lane];
        float ax = di * hv.x, ay = di * hv.y;
        int e0 = rowstart[i], e1 = rowstart[i + 1];
        for (int e = e0; e < e1; ++e) {
            int s = colidx[e];
            float ds = dinv[s];
            float2 sv = ((const float2*)(H + (size_t)s * D))[lane];
            ax = fmaf(ds, sv.x, ax);
            ay = fmaf(ds, sv.y, ay);
        }
        int b = min(max(batch[i], 0), NGRAPH - 1);
        if (b != cur) {
            atomicAdd(&pool[(size_t)cur * D + 2 * lane], acc.x);
            atomicAdd(&pool[(size_t)cur * D + 2 * lane + 1], acc.y);
            acc = make_float2(0.f, 0.f);
            cur = b;
        }
        acc.x = fmaf(di, ax, acc.x);
        acc.y = fmaf(di, ay, acc.y);
    }
    atomicAdd(&pool[(size_t)cur * D + 2 * lane], acc.x);
    atomicAdd(&pool[(size_t)cur * D + 2 * lane + 1], acc.y);
}

// --- Final tiny GEMM: out[g][o] = (pool[g]/cnt_g) . W2[:,o] + b2[o] ---------
__device__ __forceinline__ int lbound(const int* __restrict__ a, int n, int v) {
    int lo = 0, hi = n;
    while (lo < hi) {
        int m = (lo + hi) >> 1;
        if (a[m] < v) lo = m + 1; else hi = m;
    }
    return lo;
}

__global__ void final_gemm_kernel(const float* __restrict__ pool,
                                  const int* __restrict__ batch,
                                  const float* __restrict__ W2,
                                  const float* __restrict__ b2,
                                  float* __restrict__ out, int N) {
    int g = blockIdx.x, o = threadIdx.x;
    int s = lbound(batch, N, g);
    int e = lbound(batch, N, g + 1);
    float inv_cnt = 1.0f / fmaxf((float)(e - s), 1.0f);
    float acc = 0.f;
#pragma unroll 4
    for (int k = 0; k < D; ++k)
        acc = fmaf(pool[g * D + k], W2[k * D + o], acc);
    out[g * D + o] = acc * inv_cnt + b2[o];
}

// ---------------------------------------------------------------------------

extern "C" void kernel_launch(void* const* d_in, const int* in_sizes, int n_in,
                              void* d_out, int out_size, void* d_ws, size_t ws_size,
                              hipStream_t stream) {
    const float* x     = (const float*)d_in[0];   // fp32 [N,128]
    const int*   ei    = (const int*)  d_in[1];   // int32 [2,E]
    const int*   batch = (const int*)  d_in[2];   // int32 [N], sorted
    const float* W1    = (const float*)d_in[3];   // fp32 [128,128]
    const float* b1    = (const float*)d_in[4];   // fp32 [128]
    const float* W2    = (const float*)d_in[5];   // fp32 [128,128]
    const float* b2    = (const float*)d_in[6];   // fp32 [128]
    float* out = (float*)d_out;                   // fp32 [64,128]

    const int N = in_sizes[0] / D;
    const int E = in_sizes[1] / 2;

    // workspace carve-up (256B aligned) — total ~29 MB
    char* ws = (char*)d_ws;
    size_t off = 0;
    auto carve = [&](size_t bytes) {
        size_t o = off;
        off = (off + bytes + 255) & ~(size_t)255;
        return o;
    };
    size_t o_deg      = carve((size_t)N * 4);
    size_t o_rowstart = carve((size_t)(N + 1) * 4);
    size_t o_cursor   = carve((size_t)(N + 1) * 4);
    size_t o_dinv     = carve((size_t)N * 4);
    size_t o_colidx   = carve((size_t)E * 4);
    size_t o_pool     = carve((size_t)NGRAPH * D * 4);
    size_t o_agg      = carve((size_t)N * D * 4);
    size_t need = off;

    if (ws_size < need) {  // diagnostic: absmax == max|ref| signature
        zero_out_kernel<<<(out_size + 255) / 256, 256, 0, stream>>>(out, out_size);
        return;
    }

    int*   deg      = (int*)  (ws + o_deg);
    int*   rowstart = (int*)  (ws + o_rowstart);
    int*   cursor   = (int*)  (ws + o_cursor);
    float* dinv     = (float*)(ws + o_dinv);
    int*   colidx   = (int*)  (ws + o_colidx);
    float* pool     = (float*)(ws + o_pool);
    float* AGG      = (float*)(ws + o_agg);

    hipMemsetAsync(deg, 0, (size_t)N * 4, stream);
    hipMemsetAsync(pool, 0, (size_t)NGRAPH * D * 4, stream);

    int eb = (E + 255) / 256;
    count_kernel<<<eb, 256, 0, stream>>>(ei, deg, E, N);
    scan_kernel<<<1, 1024, 0, stream>>>(deg, rowstart, cursor, dinv, N);
    fill_kernel<<<eb, 256, 0, stream>>>(ei, cursor, colidx, E, N);

    int groups = AGG_BLOCKS * 4;
    int chunk  = (N + groups - 1) / groups;

    // layer 1: AGG = A_hat X
    agg1_kernel<<<AGG_BLOCKS, 256, 0, stream>>>(x, rowstart, colidx, dinv, AGG, N, chunk);
    // layer 1: AGG = relu(AGG @ W1 + b1)  (in-place, fp32 vector)
    int gb = (N + 63) / 64;
    gemm_relu_kernel<<<gb, 256, 0, stream>>>(AGG, W1, b1, N);
    // layer 2 + pool numerator
    agg2_pool_kernel<<<AGG_BLOCKS, 256, 0, stream>>>(AGG, rowstart, colidx, dinv,
                                                     batch, pool, N, chunk);
    // out = (pool/cnt) @ W2 + b2
    final_gemm_kernel<<<NGRAPH, D, 0, stream>>>(pool, batch, W2, b2, out, N);
}

// Round 5
// 307.299 us; speedup vs baseline: 2.1779x; 2.1779x over previous
//
#include <hip/hip_runtime.h>

// ---------------------------------------------------------------------------
// 2-layer GCN + global mean pool, MI355X (gfx950).  ALL-FP32.
//   A_hat = D^{-1/2}(A+I)D^{-1/2}
//   H   = relu( (A_hat X) @ W1 + b1 )        [aggregate-first, GEMM in-place]
//   out = pool( A_hat H ) @ W2 + b2          [pool-first: no relu on layer 2]
// R5: (1) GEMM restages A-tile in LDS (was global-broadcast latency-bound,
//     152us @ 11% VALUBusy); (2) single-block scan -> 3-kernel coalesced scan;
//     (3) agg kernels: 2048 blocks (full 32 waves/CU) + 2-edge unroll.
// ---------------------------------------------------------------------------

#define D 128
#define NGRAPH 64
#define AGG_BLOCKS 2048   // 8192 waves = 32/CU
#define SCAN_B 1024

// --- diagnostic: all-zero output (ws too small) ----------------------------
__global__ void zero_out_kernel(float* __restrict__ out, int n) {
    int i = blockIdx.x * blockDim.x + threadIdx.x;
    if (i < n) out[i] = 0.f;
}

// --- CSR build -------------------------------------------------------------
__global__ void count_kernel(const int* __restrict__ ei, int* __restrict__ deg,
                             int E, int N) {
    int e = blockIdx.x * blockDim.x + threadIdx.x;
    if (e < E) {
        int d = ei[E + e];  // dst
        if (d >= 0 && d < N) atomicAdd(&deg[d], 1);
    }
}

// K1: per-block inclusive scan of 1024 deg entries -> local exclusive prefix
// into rowstart[i], block total into bsum[b]. Fully coalesced.
__global__ __launch_bounds__(SCAN_B) void block_scan_kernel(const int* __restrict__ deg,
                                                            int* __restrict__ rowstart,
                                                            int* __restrict__ bsum,
                                                            int N) {
    __shared__ int sc[SCAN_B];
    int t = threadIdx.x;
    int i = blockIdx.x * SCAN_B + t;
    int v = (i < N) ? deg[i] : 0;
    int orig = v;
    sc[t] = v;
    __syncthreads();
    for (int off = 1; off < SCAN_B; off <<= 1) {
        int add = (t >= off) ? sc[t - off] : 0;
        __syncthreads();
        v += add;
        sc[t] = v;
        __syncthreads();
    }
    if (i < N) rowstart[i] = v - orig;           // local exclusive
    if (t == SCAN_B - 1) bsum[blockIdx.x] = v;   // block total
}

// K2: one wave scans <=64 block sums (shfl_up), bsum becomes exclusive block
// offsets; last lane writes the grand total to rowstart[N].
__global__ __launch_bounds__(64) void scan_sums_kernel(int* __restrict__ bsum,
                                                       int* __restrict__ rowstart,
                                                       int nblk, int N) {
    int lane = threadIdx.x;
    int v = (lane < nblk) ? bsum[lane] : 0;
    int orig = v;
    for (int off = 1; off < 64; off <<= 1) {
        int u = __shfl_up(v, off);
        if (lane >= off) v += u;
    }
    if (lane < nblk) bsum[lane] = v - orig;      // exclusive offset
    if (lane == nblk - 1) rowstart[N] = v;       // total edges
}

// K3: rowstart[i] += bsum[block]; cursor = rowstart; dinv = rsqrt(deg+1).
__global__ __launch_bounds__(SCAN_B) void finalize_scan_kernel(const int* __restrict__ deg,
                                                               const int* __restrict__ bsum,
                                                               int* __restrict__ rowstart,
                                                               int* __restrict__ cursor,
                                                               float* __restrict__ dinv,
                                                               int N) {
    int i = blockIdx.x * SCAN_B + threadIdx.x;
    if (i < N) {
        int rs = rowstart[i] + bsum[blockIdx.x];
        rowstart[i] = rs;
        cursor[i]   = rs;
        dinv[i]     = rsqrtf((float)deg[i] + 1.0f);
    }
}

__global__ void fill_kernel(const int* __restrict__ ei, int* __restrict__ cursor,
                            int* __restrict__ colidx, int E, int N) {
    int e = blockIdx.x * blockDim.x + threadIdx.x;
    if (e < E) {
        int d = ei[E + e];
        if (d >= 0 && d < N) {
            int slot = atomicAdd(&cursor[d], 1);
            if (slot >= 0 && slot < E) {
                int s = ei[e];
                colidx[slot] = min(max(s, 0), N - 1);
            }
        }
    }
}

// --- Layer-1 aggregation: AGG_i = dinv_i*(sum_e dinv_s*x_s + dinv_i*x_i) ---
// One wave per contiguous node chunk; float2/lane covers the 512B row.
__global__ __launch_bounds__(256) void agg1_kernel(const float* __restrict__ X,
                                                   const int* __restrict__ rowstart,
                                                   const int* __restrict__ colidx,
                                                   const float* __restrict__ dinv,
                                                   float* __restrict__ AGG,
                                                   int N, int chunk) {
    int gid  = blockIdx.x * 4 + (threadIdx.x >> 6);
    int lane = threadIdx.x & 63;
    int i0 = gid * chunk, i1 = min(i0 + chunk, N);
    for (int i = i0; i < i1; ++i) {
        float di = dinv[i];
        float2 xv = ((const float2*)(X + (size_t)i * D))[lane];
        float ax = di * xv.x, ay = di * xv.y;
        int e0 = rowstart[i], e1 = rowstart[i + 1];
        int e = e0;
        if ((e1 - e0) & 1) {
            int s = colidx[e++];
            float ds = dinv[s];
            float2 sv = ((const float2*)(X + (size_t)s * D))[lane];
            ax = fmaf(ds, sv.x, ax);
            ay = fmaf(ds, sv.y, ay);
        }
        for (; e < e1; e += 2) {
            int s0 = colidx[e], s1 = colidx[e + 1];
            float d0 = dinv[s0], d1 = dinv[s1];
            float2 v0 = ((const float2*)(X + (size_t)s0 * D))[lane];
            float2 v1 = ((const float2*)(X + (size_t)s1 * D))[lane];
            ax = fmaf(d0, v0.x, ax);
            ay = fmaf(d0, v0.y, ay);
            ax = fmaf(d1, v1.x, ax);
            ay = fmaf(d1, v1.y, ay);
        }
        float2 o;
        o.x = di * ax;
        o.y = di * ay;
        ((float2*)(AGG + (size_t)i * D))[lane] = o;
    }
}

// --- In-place GEMM: M = relu(M @ W1 + b1), fp32, LDS-staged A-tile ----------
// Block: 256 threads, 64-row tile. Alds[64][128] = 32 KB. Thread (tx=t&31,
// ty=t>>5) computes rows ty*8..+7 x cols tx*4..+3 (32 acc VGPRs). Inner k:
// 8 broadcast ds_read_b32 (conflict-free) + 1 L1-hit W float4 + 32 fma.
__global__ __launch_bounds__(256) void gemm_relu_kernel(float* __restrict__ M,
                                                        const float* __restrict__ W,
                                                        const float* __restrict__ bias,
                                                        int N) {
    __shared__ float Alds[64][D];
    int t = threadIdx.x;
    int row0 = blockIdx.x * 64;

    // stage: iter rr covers rows rr*8 + (t>>5); cols (t&31)*4 (float4).
    // 256 threads x 16B = 4KB contiguous per iteration -> fully coalesced.
    {
        int c4 = (t & 31) * 4;
        int rsub = t >> 5;  // 0..7
#pragma unroll
        for (int rr = 0; rr < 8; ++rr) {
            int r = rr * 8 + rsub;
            int row = row0 + r;
            if (row >= N) row = N - 1;  // duplicate tail reads, harmless
            float4 v = *(const float4*)(M + (size_t)row * D + c4);
            *(float4*)&Alds[r][c4] = v;
        }
    }
    __syncthreads();

    int tx = t & 31, ty = t >> 5;
    float4 acc[8];
#pragma unroll
    for (int r = 0; r < 8; ++r) acc[r] = make_float4(0.f, 0.f, 0.f, 0.f);

    for (int k = 0; k < D; ++k) {
        float4 w = *(const float4*)(W + (size_t)k * D + tx * 4);
#pragma unroll
        for (int r = 0; r < 8; ++r) {
            float a = Alds[ty * 8 + r][k];  // broadcast within ty group
            acc[r].x = fmaf(a, w.x, acc[r].x);
            acc[r].y = fmaf(a, w.y, acc[r].y);
            acc[r].z = fmaf(a, w.z, acc[r].z);
            acc[r].w = fmaf(a, w.w, acc[r].w);
        }
    }

    float4 bv = *(const float4*)(bias + tx * 4);
#pragma unroll
    for (int r = 0; r < 8; ++r) {
        int row = row0 + ty * 8 + r;
        if (row < N) {
            float4 o;
            o.x = fmaxf(acc[r].x + bv.x, 0.f);
            o.y = fmaxf(acc[r].y + bv.y, 0.f);
            o.z = fmaxf(acc[r].z + bv.z, 0.f);
            o.w = fmaxf(acc[r].w + bv.w, 0.f);
            *(float4*)(M + (size_t)row * D + tx * 4) = o;
        }
    }
}

// --- Layer-2 aggregation fused with pool numerator --------------------------
// batch is sorted: accumulate per-wave locally, flush on graph change.
__global__ __launch_bounds__(256) void agg2_pool_kernel(const float* __restrict__ H,
                                                        const int* __restrict__ rowstart,
                                                        const int* __restrict__ colidx,
                                                        const float* __restrict__ dinv,
                                                        const int* __restrict__ batch,
                                                        float* __restrict__ pool,
                                                        int N, int chunk) {
    int gid  = blockIdx.x * 4 + (threadIdx.x >> 6);
    int lane = threadIdx.x & 63;
    int i0 = gid * chunk, i1 = min(i0 + chunk, N);
    if (i0 >= N) return;

    float2 acc = make_float2(0.f, 0.f);
    int cur = min(max(batch[i0], 0), NGRAPH - 1);
    for (int i = i0; i < i1; ++i) {
        float di = dinv[i];
        float2 hv = ((const float2*)(H + (size_t)i * D))[lane];
        float ax = di * hv.x, ay = di * hv.y;
        int e0 = rowstart[i], e1 = rowstart[i + 1];
        int e = e0;
        if ((e1 - e0) & 1) {
            int s = colidx[e++];
            float ds = dinv[s];
            float2 sv = ((const float2*)(H + (size_t)s * D))[lane];
            ax = fmaf(ds, sv.x, ax);
            ay = fmaf(ds, sv.y, ay);
        }
        for (; e < e1; e += 2) {
            int s0 = colidx[e], s1 = colidx[e + 1];
            float d0 = dinv[s0], d1 = dinv[s1];
            float2 v0 = ((const float2*)(H + (size_t)s0 * D))[lane];
            float2 v1 = ((const float2*)(H + (size_t)s1 * D))[lane];
            ax = fmaf(d0, v0.x, ax);
            ay = fmaf(d0, v0.y, ay);
            ax = fmaf(d1, v1.x, ax);
            ay = fmaf(d1, v1.y, ay);
        }
        int b = min(max(batch[i], 0), NGRAPH - 1);
        if (b != cur) {
            atomicAdd(&pool[(size_t)cur * D + 2 * lane], acc.x);
            atomicAdd(&pool[(size_t)cur * D + 2 * lane + 1], acc.y);
            acc = make_float2(0.f, 0.f);
            cur = b;
        }
        acc.x = fmaf(di, ax, acc.x);
        acc.y = fmaf(di, ay, acc.y);
    }
    atomicAdd(&pool[(size_t)cur * D + 2 * lane], acc.x);
    atomicAdd(&pool[(size_t)cur * D + 2 * lane + 1], acc.y);
}

// --- Final tiny GEMM: out[g][o] = (pool[g]/cnt_g) . W2[:,o] + b2[o] ---------
__device__ __forceinline__ int lbound(const int* __restrict__ a, int n, int v) {
    int lo = 0, hi = n;
    while (lo < hi) {
        int m = (lo + hi) >> 1;
        if (a[m] < v) lo = m + 1; else hi = m;
    }
    return lo;
}

__global__ void final_gemm_kernel(const float* __restrict__ pool,
                                  const int* __restrict__ batch,
                                  const float* __restrict__ W2,
                                  const float* __restrict__ b2,
                                  float* __restrict__ out, int N) {
    int g = blockIdx.x, o = threadIdx.x;
    int s = lbound(batch, N, g);
    int e = lbound(batch, N, g + 1);
    float inv_cnt = 1.0f / fmaxf((float)(e - s), 1.0f);
    float acc = 0.f;
#pragma unroll 4
    for (int k = 0; k < D; ++k)
        acc = fmaf(pool[g * D + k], W2[k * D + o], acc);
    out[g * D + o] = acc * inv_cnt + b2[o];
}

// ---------------------------------------------------------------------------

extern "C" void kernel_launch(void* const* d_in, const int* in_sizes, int n_in,
                              void* d_out, int out_size, void* d_ws, size_t ws_size,
                              hipStream_t stream) {
    const float* x     = (const float*)d_in[0];   // fp32 [N,128]
    const int*   ei    = (const int*)  d_in[1];   // int32 [2,E]
    const int*   batch = (const int*)  d_in[2];   // int32 [N], sorted
    const float* W1    = (const float*)d_in[3];   // fp32 [128,128]
    const float* b1    = (const float*)d_in[4];   // fp32 [128]
    const float* W2    = (const float*)d_in[5];   // fp32 [128,128]
    const float* b2    = (const float*)d_in[6];   // fp32 [128]
    float* out = (float*)d_out;                   // fp32 [64,128]

    const int N = in_sizes[0] / D;
    const int E = in_sizes[1] / 2;
    const int nblk = (N + SCAN_B - 1) / SCAN_B;   // <=64 for N<=65536

    // workspace carve-up (256B aligned) — total ~29 MB
    char* ws = (char*)d_ws;
    size_t off = 0;
    auto carve = [&](size_t bytes) {
        size_t o = off;
        off = (off + bytes + 255) & ~(size_t)255;
        return o;
    };
    size_t o_deg      = carve((size_t)N * 4);
    size_t o_rowstart = carve((size_t)(N + 1) * 4);
    size_t o_cursor   = carve((size_t)(N + 1) * 4);
    size_t o_dinv     = carve((size_t)N * 4);
    size_t o_colidx   = carve((size_t)E * 4);
    size_t o_bsum     = carve((size_t)64 * 4);
    size_t o_pool     = carve((size_t)NGRAPH * D * 4);
    size_t o_agg      = carve((size_t)N * D * 4);
    size_t need = off;

    if (ws_size < need) {  // diagnostic: absmax == max|ref| signature
        zero_out_kernel<<<(out_size + 255) / 256, 256, 0, stream>>>(out, out_size);
        return;
    }

    int*   deg      = (int*)  (ws + o_deg);
    int*   rowstart = (int*)  (ws + o_rowstart);
    int*   cursor   = (int*)  (ws + o_cursor);
    float* dinv     = (float*)(ws + o_dinv);
    int*   colidx   = (int*)  (ws + o_colidx);
    int*   bsum     = (int*)  (ws + o_bsum);
    float* pool     = (float*)(ws + o_pool);
    float* AGG      = (float*)(ws + o_agg);

    hipMemsetAsync(deg, 0, (size_t)N * 4, stream);
    hipMemsetAsync(pool, 0, (size_t)NGRAPH * D * 4, stream);

    int eb = (E + 255) / 256;
    count_kernel<<<eb, 256, 0, stream>>>(ei, deg, E, N);
    block_scan_kernel<<<nblk, SCAN_B, 0, stream>>>(deg, rowstart, bsum, N);
    scan_sums_kernel<<<1, 64, 0, stream>>>(bsum, rowstart, nblk, N);
    finalize_scan_kernel<<<nblk, SCAN_B, 0, stream>>>(deg, bsum, rowstart, cursor, dinv, N);
    fill_kernel<<<eb, 256, 0, stream>>>(ei, cursor, colidx, E, N);

    int groups = AGG_BLOCKS * 4;
    int chunk  = (N + groups - 1) / groups;

    // layer 1: AGG = A_hat X
    agg1_kernel<<<AGG_BLOCKS, 256, 0, stream>>>(x, rowstart, colidx, dinv, AGG, N, chunk);
    // layer 1: AGG = relu(AGG @ W1 + b1)  (in-place, LDS-tiled fp32)
    int gb = (N + 63) / 64;
    gemm_relu_kernel<<<gb, 256, 0, stream>>>(AGG, W1, b1, N);
    // layer 2 + pool numerator
    agg2_pool_kernel<<<AGG_BLOCKS, 256, 0, stream>>>(AGG, rowstart, colidx, dinv,
                                                     batch, pool, N, chunk);
    // out = (pool/cnt) @ W2 + b2
    final_gemm_kernel<<<NGRAPH, D, 0, stream>>>(pool, batch, W2, b2, out, N);
}